// Round 6
// baseline (8928.078 us; speedup 1.0000x reference)
//
#include <hip/hip_runtime.h>
#include <cfloat>

namespace {

constexpr int Bb   = 4;
constexpr int Nn   = 4096;
constexpr int Cc   = 96;
constexpr int Ll   = 4;          // hops+1 slots
constexpr int NPTS = Bb * Nn;    // 16384
constexpr int C4   = Cc / 4;     // 24
constexpr int KP   = 100;        // padded LDS row stride (floats)
constexpr int NCAND = 16;        // fast-pass candidates kept per row

__device__ inline void load24f(const float* __restrict__ src, float* __restrict__ dst) {
    #pragma unroll
    for (int i = 0; i < 24; i += 4)
        *reinterpret_cast<float4*>(dst + i) = *reinterpret_cast<const float4*>(src + i);
}

// ---------------- copy xyz into stacked slot 0 ----------------
__global__ __launch_bounds__(256) void copy_xyz_kernel(const float* __restrict__ xyz,
                                                       float* __restrict__ A32) {
    int f = blockIdx.x * 256 + threadIdx.x;           // float4 index over [NPTS][C4]
    int p = f / C4;
    int c4 = f - p * C4;
    float4 v = reinterpret_cast<const float4*>(xyz)[f];
    reinterpret_cast<float4*>(A32)[(size_t)(p * Ll) * C4 + c4] = v;
}

// ---------------- np-mimic sq: numpy pairwise-8 over 96 of fl(x*x) ----------------
__global__ __launch_bounds__(256) void sqnp_kernel(const float* __restrict__ A32,
                                                   float* __restrict__ sqnp, int h) {
    int p = blockIdx.x * 256 + threadIdx.x;
    const float* x = A32 + (size_t)(p * Ll + h) * Cc;
    float r[8];
    #pragma unroll
    for (int j = 0; j < 8; ++j) r[j] = __fmul_rn(x[j], x[j]);
    #pragma unroll
    for (int i = 8; i < 96; i += 8)
        #pragma unroll
        for (int j = 0; j < 8; ++j) r[j] = __fadd_rn(r[j], __fmul_rn(x[i + j], x[i + j]));
    float L = __fadd_rn(__fadd_rn(r[0], r[1]), __fadd_rn(r[2], r[3]));
    float R = __fadd_rn(__fadd_rn(r[4], r[5]), __fadd_rn(r[6], r[7]));
    sqnp[p] = __fadd_rn(L, R);
}

// ---- np-mimic einsum dot: SSE3 SOP path — 4-lane mul+add accumulators, hadd combine ----
__device__ inline float dot_np(const float* __restrict__ xn, const float* __restrict__ xm) {
    float l0 = 0.f, l1 = 0.f, l2 = 0.f, l3 = 0.f;
    #pragma unroll 8
    for (int t = 0; t < 96; t += 4) {
        l0 = __fadd_rn(l0, __fmul_rn(xn[t],     xm[t]));
        l1 = __fadd_rn(l1, __fmul_rn(xn[t + 1], xm[t + 1]));
        l2 = __fadd_rn(l2, __fmul_rn(xn[t + 2], xm[t + 2]));
        l3 = __fadd_rn(l3, __fmul_rn(xn[t + 3], xm[t + 3]));
    }
    return __fadd_rn(__fadd_rn(l0, l1), __fadd_rn(l2, l3));
}

// ---- fused: fast fp32 dist GEMM -> top-16 cand -> np-mimic fp32 rescore ->
//      stable top-8 by (d2,idx) -> np-mimic pairwise-8 neighbor mean ----
// grid: (N/64, B), block 256.
__global__ __launch_bounds__(256) void knn_kernel(const float* __restrict__ A32,
                                                  const float* __restrict__ sqnp,
                                                  float* __restrict__ nb, int h) {
    __shared__ float a_t[64 * KP];             // later aliased: scrf[1024] | ci[1024]
    __shared__ float b_t[64 * KP];             // b tile; aliased as dist tile (stride 65)
    __shared__ float sqbf[64];
    __shared__ int   nidx[64][8];

    const int b    = blockIdx.y;
    const int row0 = blockIdx.x * 64;
    const int tid  = threadIdx.x;
    const int tx   = tid & 15;
    const int ty   = tid >> 4;

    {   // stage A rows of slot h
        int r = tid >> 2, q = tid & 3;
        load24f(A32 + (size_t)((b * Nn + row0 + r) * Ll + h) * Cc + q * 24,
                &a_t[r * KP + q * 24]);
    }

    // per-row top-16 fast candidates (wave 0, thread tid == row), (key, idx) order
    float bd[NCAND];
    int   bi[NCAND];
    #pragma unroll
    for (int q8 = 0; q8 < NCAND; ++q8) { bd[q8] = FLT_MAX; bi[q8] = 0x7fffffff; }

    for (int ct = 0; ct < Nn / 64; ++ct) {
        __syncthreads();
        {
            int r = tid >> 2, q = tid & 3;
            load24f(A32 + (size_t)((b * Nn + ct * 64 + r) * Ll + h) * Cc + q * 24,
                    &b_t[r * KP + q * 24]);
        }
        if (tid < 64) sqbf[tid] = sqnp[b * Nn + ct * 64 + tid];
        __syncthreads();

        float acc[4][4] = {};
        #pragma unroll 4
        for (int k = 0; k < Cc; k += 4) {
            float4 av[4], bv[4];
            #pragma unroll
            for (int i = 0; i < 4; ++i)
                av[i] = *reinterpret_cast<const float4*>(&a_t[(ty * 4 + i) * KP + k]);
            #pragma unroll
            for (int j = 0; j < 4; ++j)
                bv[j] = *reinterpret_cast<const float4*>(&b_t[(tx * 4 + j) * KP + k]);
            #pragma unroll
            for (int i = 0; i < 4; ++i)
                #pragma unroll
                for (int j = 0; j < 4; ++j)
                    acc[i][j] += av[i].x * bv[j].x + av[i].y * bv[j].y +
                                 av[i].z * bv[j].z + av[i].w * bv[j].w;
        }
        __syncthreads();
        #pragma unroll
        for (int i = 0; i < 4; ++i)
            #pragma unroll
            for (int j = 0; j < 4; ++j)
                b_t[(ty * 4 + i) * 65 + tx * 4 + j] = sqbf[tx * 4 + j] - 2.f * acc[i][j];
        __syncthreads();

        if (tid < 64) {
            const int base = ct * 64;
            #pragma unroll 1
            for (int j = 0; j < 64; ++j) {
                float v = b_t[tid * 65 + j];
                if (v < bd[NCAND - 1]) {
                    int vi = base + j;
                    #pragma unroll
                    for (int q8 = 0; q8 < NCAND; ++q8) {
                        if (v < bd[q8] || (v == bd[q8] && vi < bi[q8])) {
                            float tv = bd[q8]; bd[q8] = v;  v  = tv;
                            int   ti = bi[q8]; bi[q8] = vi; vi = ti;
                        }
                    }
                }
            }
        }
    }

    // ---- publish candidates, np-mimic fp32 rescore, stable top-8 ----
    __syncthreads();
    float* scrf = a_t;                       // [64][16] np-mimic d2
    int*   ci   = (int*)(a_t + 1024);        // [64][16] candidate indices
    if (tid < 64) {
        #pragma unroll
        for (int c = 0; c < NCAND; ++c) ci[tid * NCAND + c] = bi[c];
    }
    __syncthreads();
    {
        int r = tid >> 2, q = tid & 3;
        const int n_glob = b * Nn + row0 + r;
        const float* xn = A32 + (size_t)(n_glob * Ll + h) * Cc;
        const float  sqn = sqnp[n_glob];
        #pragma unroll
        for (int c = 0; c < 4; ++c) {
            int m = ci[r * NCAND + q * 4 + c];
            const float* xm = A32 + (size_t)((b * Nn + m) * Ll + h) * Cc;
            float dot = dot_np(xn, xm);
            // np: d2 = fl(fl(sq_n + sq_m) - fl(2*dot))
            scrf[r * NCAND + q * 4 + c] =
                __fsub_rn(__fadd_rn(sqn, sqnp[b * Nn + m]), __fmul_rn(2.0f, dot));
        }
    }
    __syncthreads();
    if (tid < 64) {   // stable top-8 by (d2, index) — lax.top_k tie semantics
        float sd[8]; int si[8];
        #pragma unroll
        for (int t8 = 0; t8 < 8; ++t8) { sd[t8] = FLT_MAX; si[t8] = 0x7fffffff; }
        #pragma unroll 1
        for (int c = 0; c < NCAND; ++c) {
            float v  = scrf[tid * NCAND + c];
            int   vi = ci[tid * NCAND + c];
            if (v < sd[7] || (v == sd[7] && vi < si[7])) {
                #pragma unroll
                for (int t8 = 0; t8 < 8; ++t8) {
                    if (v < sd[t8] || (v == sd[t8] && vi < si[t8])) {
                        float tv = sd[t8]; sd[t8] = v;  v  = tv;
                        int   ti = si[t8]; si[t8] = vi; vi = ti;
                    }
                }
            }
        }
        #pragma unroll
        for (int t8 = 0; t8 < 8; ++t8) nidx[tid][t8] = si[t8];
    }
    __syncthreads();

    // ---- np-mimic neighbor mean: pairwise-8 tree, x0.125 (exact /8) ----
    {
        int r = tid >> 2, q = tid & 3;
        const int n_glob = b * Nn + row0 + r;
        const float* rows[8];
        #pragma unroll
        for (int k = 0; k < 8; ++k)
            rows[k] = A32 + (size_t)((b * Nn + nidx[r][k]) * Ll + h) * Cc + q * 24;
        float* dst = nb + (size_t)n_glob * Cc + q * 24;
        #pragma unroll 4
        for (int c = 0; c < 24; ++c) {
            float L = __fadd_rn(__fadd_rn(rows[0][c], rows[1][c]),
                                __fadd_rn(rows[2][c], rows[3][c]));
            float R = __fadd_rn(__fadd_rn(rows[4][c], rows[5][c]),
                                __fadd_rn(rows[6][c], rows[7][c]));
            dst[c] = __fmul_rn(__fadd_rn(L, R), 0.125f);
        }
    }
}

// ---- np-mimic MLP GEMM: out = act(A @ W^T + bias); BLAS-style sequential-k FMA ----
// A [M][K], W [N][K], out row stride = ostride. grid (M, ceil(N/64)), block 64.
template<int K, bool LEAKY>
__global__ __launch_bounds__(64) void npgemm_kernel(const float* __restrict__ A,
                                                    const float* __restrict__ W,
                                                    const float* __restrict__ bias,
                                                    float* __restrict__ out,
                                                    int N, int ostride) {
    int i = blockIdx.x;
    int j = blockIdx.y * 64 + threadIdx.x;
    if (j >= N) return;
    const float* a = A + (size_t)i * K;
    const float* w = W + (size_t)j * K;
    float acc = 0.f;
    #pragma unroll 8
    for (int k = 0; k < K; ++k) acc = __builtin_fmaf(a[k], w[k], acc);
    float v = __fadd_rn(acc, bias[j]);
    if (LEAKY) v = v > 0.f ? v : __fmul_rn(0.2f, v);
    out[(size_t)i * ostride + j] = v;
}

// ---------------- fast fp32 GEMM (value path): out = Ain @ W^T + bias ----------------
template<int K>
__global__ __launch_bounds__(256) void gemm_kernel(const float* __restrict__ Ain,
                                                   const float* __restrict__ W,
                                                   const float* __restrict__ bias,
                                                   float* __restrict__ out,
                                                   int Nout, int out_stride) {
    __shared__ float a_t[64 * KP];
    __shared__ float w_t[64 * KP];
    const int row0 = blockIdx.x * 64;
    const int col0 = blockIdx.y * 64;
    const int tid  = threadIdx.x;
    const int tx   = tid & 15;
    const int ty   = tid >> 4;

    float acc[4][4] = {};
    for (int kt = 0; kt < K; kt += 96) {
        __syncthreads();
        {
            int r = tid >> 2, q = tid & 3;
            load24f(Ain + (size_t)(row0 + r) * K + kt + q * 24, &a_t[r * KP + q * 24]);
            float* wd = &w_t[r * KP + q * 24];
            if (col0 + r < Nout) {
                load24f(W + (size_t)(col0 + r) * K + kt + q * 24, wd);
            } else {
                #pragma unroll
                for (int i = 0; i < 24; ++i) wd[i] = 0.f;
            }
        }
        __syncthreads();
        #pragma unroll 4
        for (int k = 0; k < 96; k += 4) {
            float4 av[4], bv[4];
            #pragma unroll
            for (int i = 0; i < 4; ++i)
                av[i] = *reinterpret_cast<const float4*>(&a_t[(ty * 4 + i) * KP + k]);
            #pragma unroll
            for (int j = 0; j < 4; ++j)
                bv[j] = *reinterpret_cast<const float4*>(&w_t[(tx * 4 + j) * KP + k]);
            #pragma unroll
            for (int i = 0; i < 4; ++i)
                #pragma unroll
                for (int j = 0; j < 4; ++j)
                    acc[i][j] += av[i].x * bv[j].x + av[i].y * bv[j].y +
                                 av[i].z * bv[j].z + av[i].w * bv[j].w;
        }
    }
    #pragma unroll
    for (int i = 0; i < 4; ++i) {
        int row = row0 + ty * 4 + i;
        #pragma unroll
        for (int j = 0; j < 4; ++j) {
            int col = col0 + tx * 4 + j;
            if (col < Nout)
                out[(size_t)row * out_stride + col] = acc[i][j] + bias[col];
        }
    }
}

// ---------------- per-(point, head) MHA; mean over 4 slots folded in ----------------
__global__ __launch_bounds__(256) void attn_kernel(const float* __restrict__ qkv,
                                                   float* __restrict__ mbuf) {
    int t  = blockIdx.x * 256 + threadIdx.x;   // 4096*3 threads
    int p  = t / 3;
    int hh = t - p * 3;
    const float* base = qkv + (size_t)p * 4 * 288;
    const float* qb = base + hh * 32;
    const float* kb = base + 96 + hh * 32;
    const float* vb = base + 192 + hh * 32;

    float sc[4][4] = {};
    #pragma unroll
    for (int d = 0; d < 32; d += 4) {
        float4 qv[4], kv[4];
        #pragma unroll
        for (int l = 0; l < 4; ++l) {
            qv[l] = *reinterpret_cast<const float4*>(qb + l * 288 + d);
            kv[l] = *reinterpret_cast<const float4*>(kb + l * 288 + d);
        }
        #pragma unroll
        for (int l = 0; l < 4; ++l)
            #pragma unroll
            for (int m = 0; m < 4; ++m)
                sc[l][m] += qv[l].x * kv[m].x + qv[l].y * kv[m].y +
                            qv[l].z * kv[m].z + qv[l].w * kv[m].w;
    }
    const float scale = 0.17677669529663687f;   // 1/sqrt(32)
    float am[4] = {0.f, 0.f, 0.f, 0.f};
    #pragma unroll
    for (int l = 0; l < 4; ++l) {
        float s0 = sc[l][0] * scale, s1 = sc[l][1] * scale;
        float s2 = sc[l][2] * scale, s3 = sc[l][3] * scale;
        float mx = fmaxf(fmaxf(s0, s1), fmaxf(s2, s3));
        float e0 = expf(s0 - mx), e1 = expf(s1 - mx);
        float e2 = expf(s2 - mx), e3 = expf(s3 - mx);
        float inv = 1.f / (e0 + e1 + e2 + e3);
        am[0] += e0 * inv; am[1] += e1 * inv; am[2] += e2 * inv; am[3] += e3 * inv;
    }
    am[0] *= 0.25f; am[1] *= 0.25f; am[2] *= 0.25f; am[3] *= 0.25f;
    #pragma unroll
    for (int d = 0; d < 32; d += 4) {
        float4 o = {0.f, 0.f, 0.f, 0.f};
        #pragma unroll
        for (int m = 0; m < 4; ++m) {
            float4 v = *reinterpret_cast<const float4*>(vb + m * 288 + d);
            o.x += am[m] * v.x; o.y += am[m] * v.y;
            o.z += am[m] * v.z; o.w += am[m] * v.w;
        }
        *reinterpret_cast<float4*>(mbuf + (size_t)p * 96 + hh * 32 + d) = o;
    }
}

}  // namespace

extern "C" void kernel_launch(void* const* d_in, const int* in_sizes, int n_in,
                              void* d_out, int out_size, void* d_ws, size_t ws_size,
                              hipStream_t stream) {
    const float* xyz = (const float*)d_in[0];
    const float* W1  = (const float*)d_in[1];
    const float* b1  = (const float*)d_in[2];
    const float* W2  = (const float*)d_in[3];
    const float* b2  = (const float*)d_in[4];
    const float* ipw = (const float*)d_in[5];
    const float* ipb = (const float*)d_in[6];
    const float* opw = (const float*)d_in[7];
    const float* opb = (const float*)d_in[8];

    char* ws = (char*)d_ws;
    float* A32  = (float*)ws;                   // [65536][96] stacked feats  25.2 MB
    float* sqnp = (float*)(ws + 25165824);      // [16384]                     64 KB
    float* nb   = (float*)(ws + 25231360);      // [16384][96]                6.3 MB
    float* h1   = (float*)(ws + 31522816);      // [16384][192]              12.6 MB
    float* qkvc = (float*)(ws + 44105728);      // [16384][288] per-batch    18.9 MB
    float* mbuf = (float*)(ws + 62980096);      // [16384][96]                6.3 MB

    copy_xyz_kernel<<<1536, 256, 0, stream>>>(xyz, A32);

    for (int h = 0; h < 3; ++h) {
        sqnp_kernel<<<64, 256, 0, stream>>>(A32, sqnp, h);
        knn_kernel<<<dim3(Nn / 64, Bb), 256, 0, stream>>>(A32, sqnp, nb, h);
        npgemm_kernel<96, true><<<dim3(NPTS, 3), 64, 0, stream>>>(
            nb, W1 + (size_t)h * 192 * 96, b1 + h * 192, h1, 192, 192);
        npgemm_kernel<192, false><<<dim3(NPTS, 2), 64, 0, stream>>>(
            h1, W2 + (size_t)h * 96 * 192, b2 + h * 96, A32 + (h + 1) * 96, 96, Ll * Cc);
    }

    // MHA (value path), chunked per batch
    for (int b = 0; b < Bb; ++b) {
        gemm_kernel<96><<<dim3(16384 / 64, 5), 256, 0, stream>>>(
            A32 + (size_t)b * 4096 * Ll * Cc, ipw, ipb, qkvc, 288, 288);
        attn_kernel<<<48, 256, 0, stream>>>(qkvc, mbuf + (size_t)b * 4096 * 96);
    }

    gemm_kernel<96><<<dim3(NPTS / 64, 2), 256, 0, stream>>>(
        mbuf, opw, opb, (float*)d_out, 96, 96);
}

// Round 7
// 4677.982 us; speedup vs baseline: 1.9085x; 1.9085x over previous
//
#include <hip/hip_runtime.h>
#include <cfloat>

namespace {

constexpr int Bb    = 4;
constexpr int Nn    = 4096;
constexpr int Cc    = 96;
constexpr int Ll    = 4;          // hops+1 slots
constexpr int NPTS  = Bb * Nn;    // 16384
constexpr int C4    = Cc / 4;     // 24
constexpr int KP    = 100;        // padded LDS row stride (floats)
constexpr int CS    = 2;          // column splits (grid.z)
constexpr int TK    = 12;         // per-stream fast candidates
constexpr int NCROW = CS * 4 * TK; // 96 candidates per row
constexpr int DP    = 68;         // dist tile row stride (16B-aligned rows)

// ---- swizzled tile staging: granule g of row r stored at column (g ^ ((r>>2)&7)) ----
// Kills the 8-way ds_read bank conflict of stride-400 row access (lanes then spread
// start-banks via the XOR; 2-way residue is free on CDNA4).
__device__ inline void stage_row(const float* __restrict__ src, float* __restrict__ tile,
                                 int r, int q) {
    const int s = (r >> 2) & 7;
    #pragma unroll
    for (int m = 0; m < 6; ++m) {
        int g = q * 6 + m;
        float4 v = reinterpret_cast<const float4*>(src)[g];
        *reinterpret_cast<float4*>(&tile[r * KP + ((g ^ s) << 2)]) = v;
    }
}

// ---------------- copy xyz into stacked slot 0 ----------------
__global__ __launch_bounds__(256) void copy_xyz_kernel(const float* __restrict__ xyz,
                                                       float* __restrict__ A32) {
    int f = blockIdx.x * 256 + threadIdx.x;           // float4 index over [NPTS][C4]
    int p = f / C4;
    int c4 = f - p * C4;
    float4 v = reinterpret_cast<const float4*>(xyz)[f];
    reinterpret_cast<float4*>(A32)[(size_t)(p * Ll) * C4 + c4] = v;
}

// ---------------- np-mimic sq: numpy pairwise-8 over 96 of fl(x*x) ----------------
__global__ __launch_bounds__(256) void sqnp_kernel(const float* __restrict__ A32,
                                                   float* __restrict__ sqnp, int h) {
    int p = blockIdx.x * 256 + threadIdx.x;
    const float* x = A32 + (size_t)(p * Ll + h) * Cc;
    float r[8];
    #pragma unroll
    for (int j = 0; j < 8; ++j) r[j] = __fmul_rn(x[j], x[j]);
    #pragma unroll
    for (int i = 8; i < 96; i += 8)
        #pragma unroll
        for (int j = 0; j < 8; ++j) r[j] = __fadd_rn(r[j], __fmul_rn(x[i + j], x[i + j]));
    float L = __fadd_rn(__fadd_rn(r[0], r[1]), __fadd_rn(r[2], r[3]));
    float R = __fadd_rn(__fadd_rn(r[4], r[5]), __fadd_rn(r[6], r[7]));
    sqnp[p] = __fadd_rn(L, R);
}

// ---- np-mimic einsum dot: SSE SOP path — 4-lane mul+add accumulators, hadd combine ----
__device__ inline float dot_np(const float* __restrict__ xn, const float* __restrict__ xm) {
    float l0 = 0.f, l1 = 0.f, l2 = 0.f, l3 = 0.f;
    #pragma unroll
    for (int t = 0; t < 96; t += 4) {
        float4 a = *reinterpret_cast<const float4*>(xn + t);
        float4 c = *reinterpret_cast<const float4*>(xm + t);
        l0 = __fadd_rn(l0, __fmul_rn(a.x, c.x));
        l1 = __fadd_rn(l1, __fmul_rn(a.y, c.y));
        l2 = __fadd_rn(l2, __fmul_rn(a.z, c.z));
        l3 = __fadd_rn(l3, __fmul_rn(a.w, c.w));
    }
    return __fadd_rn(__fadd_rn(l0, l1), __fadd_rn(l2, l3));
}

// ---- fast fp32 dist GEMM + per-stream top-12 candidate collection ----
// grid (Nn/64 row-tiles, Bb, CS), block 256. Each thread scans a fixed
// (row, 16-col quarter) stream over its column half; union of 4x12x2 = 96
// candidates/row is a guaranteed superset of the np top-8 (stream-rank <= 9).
__global__ __launch_bounds__(256) void knn_cand_kernel(const float* __restrict__ A32,
                                                       const float* __restrict__ sqnp,
                                                       int* __restrict__ cand, int h) {
    __shared__ float a_t[64 * KP];
    __shared__ float b_t[64 * KP];       // aliased as dist tile [64][DP] after GEMM
    __shared__ float sqbf[64];

    const int b     = blockIdx.y;
    const int cs    = blockIdx.z;
    const int row0  = blockIdx.x * 64;
    const int col00 = cs * (Nn / CS);
    const int tid   = threadIdx.x;
    const int tx    = tid & 15;
    const int ty    = tid >> 4;

    {   // stage A rows (swizzled)
        int r = tid >> 2, q = tid & 3;
        stage_row(A32 + (size_t)((b * Nn + row0 + r) * Ll + h) * Cc, a_t, r, q);
    }

    const int r_s = tid & 63;        // scan row (one per lane across the block)
    const int qq  = tid >> 6;        // scan quarter (one per wave)
    float bd[TK]; int bi[TK];
    #pragma unroll
    for (int t = 0; t < TK; ++t) { bd[t] = FLT_MAX; bi[t] = 0x7fffffff; }

    for (int ct = 0; ct < (Nn / CS) / 64; ++ct) {
        __syncthreads();             // prev scan done; b_t reusable
        {
            int r = tid >> 2, q = tid & 3;
            stage_row(A32 + (size_t)((b * Nn + col00 + ct * 64 + r) * Ll + h) * Cc,
                      b_t, r, q);
        }
        if (tid < 64) sqbf[tid] = sqnp[b * Nn + col00 + ct * 64 + tid];
        __syncthreads();

        float acc[4][4] = {};
        const int sa = ty & 7, sb = tx & 7;
        #pragma unroll 4
        for (int k4 = 0; k4 < 24; ++k4) {
            float4 av[4], bv[4];
            const int ga = (k4 ^ sa) << 2, gb = (k4 ^ sb) << 2;
            #pragma unroll
            for (int i = 0; i < 4; ++i)
                av[i] = *reinterpret_cast<const float4*>(&a_t[(ty * 4 + i) * KP + ga]);
            #pragma unroll
            for (int j = 0; j < 4; ++j)
                bv[j] = *reinterpret_cast<const float4*>(&b_t[(tx * 4 + j) * KP + gb]);
            #pragma unroll
            for (int i = 0; i < 4; ++i)
                #pragma unroll
                for (int j = 0; j < 4; ++j)
                    acc[i][j] += av[i].x * bv[j].x + av[i].y * bv[j].y +
                                 av[i].z * bv[j].z + av[i].w * bv[j].w;
        }
        __syncthreads();             // all GEMM reads of b_t done; alias as dist
        #pragma unroll
        for (int i = 0; i < 4; ++i) {
            float4 dv;
            dv.x = sqbf[tx * 4 + 0] - 2.f * acc[i][0];
            dv.y = sqbf[tx * 4 + 1] - 2.f * acc[i][1];
            dv.z = sqbf[tx * 4 + 2] - 2.f * acc[i][2];
            dv.w = sqbf[tx * 4 + 3] - 2.f * acc[i][3];
            *reinterpret_cast<float4*>(&b_t[(ty * 4 + i) * DP + tx * 4]) = dv;
        }
        __syncthreads();

        // scan: 16 columns of this tile, stream index strictly increasing
        const int cbase = col00 + ct * 64 + qq * 16;
        #pragma unroll 1
        for (int jj = 0; jj < 16; ++jj) {
            float v = b_t[r_s * DP + qq * 16 + jj];
            if (v < bd[TK - 1]) {    // incoming idx > all stored: strict < is correct
                int vi = cbase + jj;
                #pragma unroll
                for (int t = 0; t < TK; ++t) {
                    if (v < bd[t] || (v == bd[t] && vi < bi[t])) {
                        float tv = bd[t]; bd[t] = v;  v  = tv;
                        int   ti = bi[t]; bi[t] = vi; vi = ti;
                    }
                }
            }
        }
    }

    const int prow = b * Nn + row0 + r_s;
    #pragma unroll
    for (int t = 0; t < TK; ++t)
        cand[(size_t)prow * NCROW + (cs * 4 + qq) * TK + t] = bi[t];
}

// ---- np-exact rescore of 96 candidates -> stable top-8 by (d2, idx) ----
__global__ __launch_bounds__(256) void rescore_kernel(const float* __restrict__ A32,
                                                      const float* __restrict__ sqnp,
                                                      const int* __restrict__ cand,
                                                      int* __restrict__ nidx, int h) {
    const int p = blockIdx.x * 256 + threadIdx.x;     // 16384 rows
    const int b = p >> 12;
    const int base = b * Nn;
    const float* xn = A32 + (size_t)(p * Ll + h) * Cc;
    const float sqn = sqnp[p];
    const int* cp = cand + (size_t)p * NCROW;

    float sd[8]; int si[8];
    #pragma unroll
    for (int t = 0; t < 8; ++t) { sd[t] = FLT_MAX; si[t] = 0x7fffffff; }

    #pragma unroll 1
    for (int c = 0; c < NCROW; ++c) {
        int m = cp[c];
        const float* xm = A32 + (size_t)((base + m) * Ll + h) * Cc;
        float dot = dot_np(xn, xm);
        // np: d2 = fl(fl(sq_n + sq_m) - fl(2*dot))
        float v = __fsub_rn(__fadd_rn(sqn, sqnp[base + m]), __fmul_rn(2.0f, dot));
        if (v < sd[7] || (v == sd[7] && m < si[7])) {   // lexicographic, order-independent
            int vi = m;
            #pragma unroll
            for (int t = 0; t < 8; ++t) {
                if (v < sd[t] || (v == sd[t] && vi < si[t])) {
                    float tv = sd[t]; sd[t] = v;  v  = tv;
                    int   ti = si[t]; si[t] = vi; vi = ti;
                }
            }
        }
    }
    #pragma unroll
    for (int t = 0; t < 8; ++t) nidx[(size_t)p * 8 + t] = si[t];
}

// ---- np-mimic neighbor mean: pairwise-8 tree, x0.125 ----
__global__ __launch_bounds__(256) void mean_kernel(const float* __restrict__ A32,
                                                   const int* __restrict__ nidx,
                                                   float* __restrict__ nb, int h) {
    const int p = blockIdx.x * 64 + (threadIdx.x >> 2);
    const int q = threadIdx.x & 3;
    const int b = p >> 12;
    const float* rows[8];
    #pragma unroll
    for (int k = 0; k < 8; ++k)
        rows[k] = A32 + (size_t)((b * Nn + nidx[(size_t)p * 8 + k]) * Ll + h) * Cc + q * 24;
    float* dst = nb + (size_t)p * Cc + q * 24;
    #pragma unroll 4
    for (int c = 0; c < 24; ++c) {
        float L = __fadd_rn(__fadd_rn(rows[0][c], rows[1][c]),
                            __fadd_rn(rows[2][c], rows[3][c]));
        float R = __fadd_rn(__fadd_rn(rows[4][c], rows[5][c]),
                            __fadd_rn(rows[6][c], rows[7][c]));
        dst[c] = __fmul_rn(__fadd_rn(L, R), 0.125f);
    }
}

// ---- np-mimic MLP GEMM: out = act(A @ W^T + bias); BLAS-style sequential-k FMA ----
// block (64,4): thread = (j = bx*64+tx, i = by*4+ty). Same scalar chain as before.
template<int K, bool LEAKY>
__global__ __launch_bounds__(256) void npgemm_kernel(const float* __restrict__ A,
                                                     const float* __restrict__ W,
                                                     const float* __restrict__ bias,
                                                     float* __restrict__ out,
                                                     int N, int ostride) {
    int j = blockIdx.x * 64 + threadIdx.x;
    int i = blockIdx.y * 4 + threadIdx.y;
    if (j >= N) return;
    const float* a = A + (size_t)i * K;
    const float* w = W + (size_t)j * K;
    float acc = 0.f;
    #pragma unroll 8
    for (int k = 0; k < K; ++k) acc = __builtin_fmaf(a[k], w[k], acc);
    float v = __fadd_rn(acc, bias[j]);
    if (LEAKY) v = v > 0.f ? v : __fmul_rn(0.2f, v);
    out[(size_t)i * ostride + j] = v;
}

// ---------------- fast fp32 GEMM (value path): out = Ain @ W^T + bias ----------------
template<int K>
__global__ __launch_bounds__(256) void gemm_kernel(const float* __restrict__ Ain,
                                                   const float* __restrict__ W,
                                                   const float* __restrict__ bias,
                                                   float* __restrict__ out,
                                                   int Nout, int out_stride) {
    __shared__ float a_t[64 * KP];
    __shared__ float w_t[64 * KP];
    const int row0 = blockIdx.x * 64;
    const int col0 = blockIdx.y * 64;
    const int tid  = threadIdx.x;
    const int tx   = tid & 15;
    const int ty   = tid >> 4;

    float acc[4][4] = {};
    for (int kt = 0; kt < K; kt += 96) {
        __syncthreads();
        {
            int r = tid >> 2, q = tid & 3;
            stage_row(Ain + (size_t)(row0 + r) * K + kt, a_t, r, q);
            if (col0 + r < Nout) {
                stage_row(W + (size_t)(col0 + r) * K + kt, w_t, r, q);
            } else {
                const int s = (r >> 2) & 7;
                #pragma unroll
                for (int m = 0; m < 6; ++m) {
                    int g = q * 6 + m;
                    *reinterpret_cast<float4*>(&w_t[r * KP + ((g ^ s) << 2)]) =
                        float4{0.f, 0.f, 0.f, 0.f};
                }
            }
        }
        __syncthreads();
        const int sa = ty & 7, sb = tx & 7;
        #pragma unroll 4
        for (int k4 = 0; k4 < 24; ++k4) {
            float4 av[4], bv[4];
            const int ga = (k4 ^ sa) << 2, gb = (k4 ^ sb) << 2;
            #pragma unroll
            for (int i = 0; i < 4; ++i)
                av[i] = *reinterpret_cast<const float4*>(&a_t[(ty * 4 + i) * KP + ga]);
            #pragma unroll
            for (int j = 0; j < 4; ++j)
                bv[j] = *reinterpret_cast<const float4*>(&w_t[(tx * 4 + j) * KP + gb]);
            #pragma unroll
            for (int i = 0; i < 4; ++i)
                #pragma unroll
                for (int j = 0; j < 4; ++j)
                    acc[i][j] += av[i].x * bv[j].x + av[i].y * bv[j].y +
                                 av[i].z * bv[j].z + av[i].w * bv[j].w;
        }
    }
    #pragma unroll
    for (int i = 0; i < 4; ++i) {
        int row = row0 + ty * 4 + i;
        #pragma unroll
        for (int j = 0; j < 4; ++j) {
            int col = col0 + tx * 4 + j;
            if (col < Nout)
                out[(size_t)row * out_stride + col] = acc[i][j] + bias[col];
        }
    }
}

// ---------------- per-(point, head) MHA; mean over 4 slots folded in ----------------
__global__ __launch_bounds__(256) void attn_kernel(const float* __restrict__ qkv,
                                                   float* __restrict__ mbuf) {
    int t  = blockIdx.x * 256 + threadIdx.x;   // 4096*3 threads
    int p  = t / 3;
    int hh = t - p * 3;
    const float* base = qkv + (size_t)p * 4 * 288;
    const float* qb = base + hh * 32;
    const float* kb = base + 96 + hh * 32;
    const float* vb = base + 192 + hh * 32;

    float sc[4][4] = {};
    #pragma unroll
    for (int d = 0; d < 32; d += 4) {
        float4 qv[4], kv[4];
        #pragma unroll
        for (int l = 0; l < 4; ++l) {
            qv[l] = *reinterpret_cast<const float4*>(qb + l * 288 + d);
            kv[l] = *reinterpret_cast<const float4*>(kb + l * 288 + d);
        }
        #pragma unroll
        for (int l = 0; l < 4; ++l)
            #pragma unroll
            for (int m = 0; m < 4; ++m)
                sc[l][m] += qv[l].x * kv[m].x + qv[l].y * kv[m].y +
                            qv[l].z * kv[m].z + qv[l].w * kv[m].w;
    }
    const float scale = 0.17677669529663687f;   // 1/sqrt(32)
    float am[4] = {0.f, 0.f, 0.f, 0.f};
    #pragma unroll
    for (int l = 0; l < 4; ++l) {
        float s0 = sc[l][0] * scale, s1 = sc[l][1] * scale;
        float s2 = sc[l][2] * scale, s3 = sc[l][3] * scale;
        float mx = fmaxf(fmaxf(s0, s1), fmaxf(s2, s3));
        float e0 = expf(s0 - mx), e1 = expf(s1 - mx);
        float e2 = expf(s2 - mx), e3 = expf(s3 - mx);
        float inv = 1.f / (e0 + e1 + e2 + e3);
        am[0] += e0 * inv; am[1] += e1 * inv; am[2] += e2 * inv; am[3] += e3 * inv;
    }
    am[0] *= 0.25f; am[1] *= 0.25f; am[2] *= 0.25f; am[3] *= 0.25f;
    #pragma unroll
    for (int d = 0; d < 32; d += 4) {
        float4 o = {0.f, 0.f, 0.f, 0.f};
        #pragma unroll
        for (int m = 0; m < 4; ++m) {
            float4 v = *reinterpret_cast<const float4*>(vb + m * 288 + d);
            o.x += am[m] * v.x; o.y += am[m] * v.y;
            o.z += am[m] * v.z; o.w += am[m] * v.w;
        }
        *reinterpret_cast<float4*>(mbuf + (size_t)p * 96 + hh * 32 + d) = o;
    }
}

}  // namespace

extern "C" void kernel_launch(void* const* d_in, const int* in_sizes, int n_in,
                              void* d_out, int out_size, void* d_ws, size_t ws_size,
                              hipStream_t stream) {
    const float* xyz = (const float*)d_in[0];
    const float* W1  = (const float*)d_in[1];
    const float* b1  = (const float*)d_in[2];
    const float* W2  = (const float*)d_in[3];
    const float* b2  = (const float*)d_in[4];
    const float* ipw = (const float*)d_in[5];
    const float* ipb = (const float*)d_in[6];
    const float* opw = (const float*)d_in[7];
    const float* opb = (const float*)d_in[8];

    char* ws = (char*)d_ws;
    float* A32  = (float*)ws;                   // [65536][96]           25.2 MB
    float* sqnp = (float*)(ws + 25165824);      // [16384]                64 KB
    int*   cand = (int*)  (ws + 25231360);      // [16384][96]           6.3 MB
    int*   nidx = (int*)  (ws + 31522816);      // [16384][8]            512 KB
    float* nb   = (float*)(ws + 32047104);      // [16384][96]           6.3 MB
    float* h1   = (float*)(ws + 38338560);      // [16384][192]         12.6 MB
    float* qkvc = (float*)(ws + 50921472);      // [16384][288]         18.9 MB
    float* mbuf = (float*)(ws + 69795840);      // [16384][96]           6.3 MB
    // total ~76.1 MB

    copy_xyz_kernel<<<1536, 256, 0, stream>>>(xyz, A32);

    for (int h = 0; h < 3; ++h) {
        sqnp_kernel<<<64, 256, 0, stream>>>(A32, sqnp, h);
        knn_cand_kernel<<<dim3(Nn / 64, Bb, CS), 256, 0, stream>>>(A32, sqnp, cand, h);
        rescore_kernel<<<NPTS / 256, 256, 0, stream>>>(A32, sqnp, cand, nidx, h);
        mean_kernel<<<NPTS / 64, 256, 0, stream>>>(A32, nidx, nb, h);
        npgemm_kernel<96, true><<<dim3(3, NPTS / 4), dim3(64, 4), 0, stream>>>(
            nb, W1 + (size_t)h * 192 * 96, b1 + h * 192, h1, 192, 192);
        npgemm_kernel<192, false><<<dim3(2, NPTS / 4), dim3(64, 4), 0, stream>>>(
            h1, W2 + (size_t)h * 96 * 192, b2 + h * 96, A32 + (h + 1) * 96, 96, Ll * Cc);
    }

    // MHA (value path), chunked per batch
    for (int b = 0; b < Bb; ++b) {
        gemm_kernel<96><<<dim3(16384 / 64, 5), 256, 0, stream>>>(
            A32 + (size_t)b * 4096 * Ll * Cc, ipw, ipb, qkvc, 288, 288);
        attn_kernel<<<48, 256, 0, stream>>>(qkvc, mbuf + (size_t)b * 4096 * 96);
    }

    gemm_kernel<96><<<dim3(NPTS / 64, 2), 256, 0, stream>>>(
        mbuf, opw, opb, (float*)d_out, 96, 96);
}

// Round 8
// 4055.586 us; speedup vs baseline: 2.2014x; 1.1535x over previous
//
#include <hip/hip_runtime.h>
#include <cfloat>

namespace {

constexpr int Bb    = 4;
constexpr int Nn    = 4096;
constexpr int Cc    = 96;
constexpr int Ll    = 4;           // hops+1 slots
constexpr int NPTS  = Bb * Nn;     // 16384
constexpr int C4    = Cc / 4;      // 24
constexpr int KP    = 100;         // padded LDS row stride (floats) for fp32 gemm
constexpr int NCROW = 48;          // candidates per row (4 lanes x top-12)
constexpr int TK    = 12;          // per-lane candidates
constexpr int LP    = 104;         // bf16 LDS row pitch (208 B; 52 words, spreads banks)

typedef __attribute__((ext_vector_type(8))) short bf16x8;
typedef __attribute__((ext_vector_type(4))) float f32x4;

// RNE fp32 -> bf16 (rounding mode irrelevant: candidate ranking only)
__device__ inline ushort f2bf(float x) {
    unsigned u = __float_as_uint(x);
    return (ushort)((u + 0x7FFF + ((u >> 16) & 1)) >> 16);
}

// lexicographic (value, index) sorted-insert into ascending top-T
template<int T>
__device__ inline void lexins(float v, int vi, float (&bd)[T], int (&bi)[T]) {
    if (v < bd[T - 1] || (v == bd[T - 1] && vi < bi[T - 1])) {
        #pragma unroll
        for (int t = 0; t < T; ++t) {
            if (v < bd[t] || (v == bd[t] && vi < bi[t])) {
                float tv = bd[t]; bd[t] = v;  v  = tv;
                int   ti = bi[t]; bi[t] = vi; vi = ti;
            }
        }
    }
}

// ---------------- copy xyz into stacked slot 0 ----------------
__global__ __launch_bounds__(256) void copy_xyz_kernel(const float* __restrict__ xyz,
                                                       float* __restrict__ A32) {
    int f = blockIdx.x * 256 + threadIdx.x;           // float4 index over [NPTS][C4]
    int p = f / C4;
    int c4 = f - p * C4;
    float4 v = reinterpret_cast<const float4*>(xyz)[f];
    reinterpret_cast<float4*>(A32)[(size_t)(p * Ll) * C4 + c4] = v;
}

// ---------------- np-mimic sq: numpy pairwise-8 over 96 of fl(x*x) ----------------
__global__ __launch_bounds__(256) void sqnp_kernel(const float* __restrict__ A32,
                                                   float* __restrict__ sqnp, int h) {
    int p = blockIdx.x * 256 + threadIdx.x;
    const float* x = A32 + (size_t)(p * Ll + h) * Cc;
    float r[8];
    #pragma unroll
    for (int j = 0; j < 8; ++j) r[j] = __fmul_rn(x[j], x[j]);
    #pragma unroll
    for (int i = 8; i < 96; i += 8)
        #pragma unroll
        for (int j = 0; j < 8; ++j) r[j] = __fadd_rn(r[j], __fmul_rn(x[i + j], x[i + j]));
    float L = __fadd_rn(__fadd_rn(r[0], r[1]), __fadd_rn(r[2], r[3]));
    float R = __fadd_rn(__fadd_rn(r[4], r[5]), __fadd_rn(r[6], r[7]));
    sqnp[p] = __fadd_rn(L, R);
}

// ---------------- fp32 slot h -> bf16 feature matrix A16[16384][96] ----------------
__global__ __launch_bounds__(256) void cvt_kernel(const float* __restrict__ A32,
                                                  ushort* __restrict__ A16, int h) {
    int t = blockIdx.x * 256 + threadIdx.x;           // 16384*12 groups of 8 elems
    int p = t / 12, j = t - p * 12;
    const float4* s = reinterpret_cast<const float4*>(A32 + (size_t)(p * Ll + h) * Cc + j * 8);
    float4 v0 = s[0], v1 = s[1];
    uint4 o;
    o.x = (unsigned)f2bf(v0.x) | ((unsigned)f2bf(v0.y) << 16);
    o.y = (unsigned)f2bf(v0.z) | ((unsigned)f2bf(v0.w) << 16);
    o.z = (unsigned)f2bf(v1.x) | ((unsigned)f2bf(v1.y) << 16);
    o.w = (unsigned)f2bf(v1.z) | ((unsigned)f2bf(v1.w) << 16);
    *reinterpret_cast<uint4*>(A16 + (size_t)p * 96 + j * 8) = o;
}

// ---- MFMA candidate pass: D[db][q] = DB·Q^T via 16x16x32 bf16; per-lane top-12 ----
// Block = 64 queries (4 waves x 16), db = full 4096 of the query's batch, chunks of 64.
// C-layout (m89): col=lane&15 (query), row=(lane>>4)*4+reg (db) -> each lane owns one
// query column and a fixed db-row class; its register top-12 needs no cross-lane merge.
__global__ __launch_bounds__(256) void knn_mfma_kernel(const ushort* __restrict__ A16,
                                                       const float* __restrict__ sqnp,
                                                       int* __restrict__ cand) {
    __shared__ ushort qt[64 * LP];          // 13312 B
    __shared__ ushort dbt[2][64 * LP];      // 26624 B (double buffer)
    __shared__ float  sqf[2][64];

    const int q0    = blockIdx.x * 64;
    const int pbase = (q0 >> 12) << 12;     // batch base
    const int tid   = threadIdx.x;
    const int w     = tid >> 6;
    const int l     = tid & 63;

    {   // stage Q tile + chunk 0 (rows 16B-aligned: 192B pitch src, 208B pitch dst)
        int r = tid >> 2, q = tid & 3;
        const uint4* s = reinterpret_cast<const uint4*>(A16 + (size_t)(q0 + r) * 96 + q * 24);
        uint4* d = reinterpret_cast<uint4*>(qt + r * LP + q * 24);
        d[0] = s[0]; d[1] = s[1]; d[2] = s[2];
        const uint4* s2 = reinterpret_cast<const uint4*>(A16 + (size_t)(pbase + r) * 96 + q * 24);
        uint4* d2 = reinterpret_cast<uint4*>(dbt[0] + r * LP + q * 24);
        d2[0] = s2[0]; d2[1] = s2[1]; d2[2] = s2[2];
    }
    if (tid < 64) sqf[0][tid] = sqnp[pbase + tid];
    __syncthreads();

    // B fragments (this wave's 16 queries), constant across chunks.
    // A/B frag layout: lane holds 8 contiguous bf16 at k = (lane>>4)*8 (+32 per slice).
    const int qrow = w * 16 + (l & 15);
    const int koff = (l >> 4) * 8;
    bf16x8 bq[3];
    #pragma unroll
    for (int s = 0; s < 3; ++s)
        bq[s] = *reinterpret_cast<const bf16x8*>(qt + qrow * LP + koff + 32 * s);

    float bd[TK]; int bi[TK];
    #pragma unroll
    for (int t = 0; t < TK; ++t) { bd[t] = FLT_MAX; bi[t] = 0x7fffffff; }

    for (int c = 0; c < Nn / 64; ++c) {
        const int buf = c & 1;
        if (c + 1 < Nn / 64) {   // prefetch next chunk into other buffer
            int r = tid >> 2, q = tid & 3;
            const uint4* s = reinterpret_cast<const uint4*>(
                A16 + (size_t)(pbase + (c + 1) * 64 + r) * 96 + q * 24);
            uint4* d = reinterpret_cast<uint4*>(dbt[buf ^ 1] + r * LP + q * 24);
            d[0] = s[0]; d[1] = s[1]; d[2] = s[2];
            if (tid < 64) sqf[buf ^ 1][tid] = sqnp[pbase + (c + 1) * 64 + tid];
        }

        f32x4 acc[4];
        #pragma unroll
        for (int sub = 0; sub < 4; ++sub) {
            acc[sub] = f32x4{0.f, 0.f, 0.f, 0.f};
            #pragma unroll
            for (int s = 0; s < 3; ++s) {
                bf16x8 a = *reinterpret_cast<const bf16x8*>(
                    dbt[buf] + (sub * 16 + (l & 15)) * LP + koff + 32 * s);
                acc[sub] = __builtin_amdgcn_mfma_f32_16x16x32_bf16(a, bq[s], acc[sub], 0, 0, 0);
            }
        }
        // keys (fast fp32; ranking only) + per-lane top-12. idx ascending in-stream.
        #pragma unroll
        for (int sub = 0; sub < 4; ++sub)
            #pragma unroll
            for (int r = 0; r < 4; ++r) {
                int dl = sub * 16 + (l >> 4) * 4 + r;
                float v = sqf[buf][dl] - 2.f * acc[sub][r];
                lexins<TK>(v, c * 64 + dl, bd, bi);
            }
        __syncthreads();   // chunk consumed; prefetched buffer complete
    }

    const int qg = q0 + qrow;
    #pragma unroll
    for (int t = 0; t < TK; ++t)
        cand[(size_t)qg * NCROW + (l >> 4) * TK + t] = bi[t];
}

// ---- np-mimic einsum dot: SSE SOP path — 4-lane mul+add accumulators, hadd combine ----
__device__ inline float dot_np(const float* __restrict__ xn, const float* __restrict__ xm) {
    float l0 = 0.f, l1 = 0.f, l2 = 0.f, l3 = 0.f;
    #pragma unroll
    for (int t = 0; t < 96; t += 4) {
        float4 a = *reinterpret_cast<const float4*>(xn + t);
        float4 c = *reinterpret_cast<const float4*>(xm + t);
        l0 = __fadd_rn(l0, __fmul_rn(a.x, c.x));
        l1 = __fadd_rn(l1, __fmul_rn(a.y, c.y));
        l2 = __fadd_rn(l2, __fmul_rn(a.z, c.z));
        l3 = __fadd_rn(l3, __fmul_rn(a.w, c.w));
    }
    return __fadd_rn(__fadd_rn(l0, l1), __fadd_rn(l2, l3));
}

// ---- np-exact rescore of 48 candidates -> stable top-8 by (d2, idx) ----
// 8 threads per query score 6 candidates each; thread 0 of the 8 merges.
__global__ __launch_bounds__(256) void rescore_kernel(const float* __restrict__ A32,
                                                      const float* __restrict__ sqnp,
                                                      const int* __restrict__ cand,
                                                      int* __restrict__ nidx, int h) {
    __shared__ float sc[32][NCROW];
    const int tid  = threadIdx.x;
    const int qloc = tid >> 3, sub = tid & 7;
    const int p    = blockIdx.x * 32 + qloc;
    const int base = (p >> 12) << 12;
    const float* xn = A32 + (size_t)(p * Ll + h) * Cc;
    const float sqn = sqnp[p];
    const int* cp = cand + (size_t)p * NCROW;

    #pragma unroll
    for (int c = 0; c < 6; ++c) {
        int m = cp[sub * 6 + c];
        const float* xm = A32 + (size_t)((base + m) * Ll + h) * Cc;
        float dot = dot_np(xn, xm);
        // np: d2 = fl(fl(sq_n + sq_m) - fl(2*dot))
        sc[qloc][sub * 6 + c] =
            __fsub_rn(__fadd_rn(sqn, sqnp[base + m]), __fmul_rn(2.0f, dot));
    }
    __syncthreads();
    if (sub == 0) {
        float sd[8]; int si[8];
        #pragma unroll
        for (int t = 0; t < 8; ++t) { sd[t] = FLT_MAX; si[t] = 0x7fffffff; }
        #pragma unroll 1
        for (int c = 0; c < NCROW; ++c) lexins<8>(sc[qloc][c], cp[c], sd, si);
        #pragma unroll
        for (int t = 0; t < 8; ++t) nidx[(size_t)p * 8 + t] = si[t];
    }
}

// ---- np-mimic neighbor mean: pairwise-8 tree, x0.125 ----
__global__ __launch_bounds__(256) void mean_kernel(const float* __restrict__ A32,
                                                   const int* __restrict__ nidx,
                                                   float* __restrict__ nb, int h) {
    const int p = blockIdx.x * 64 + (threadIdx.x >> 2);
    const int q = threadIdx.x & 3;
    const int b = p >> 12;
    const float* rows[8];
    #pragma unroll
    for (int k = 0; k < 8; ++k)
        rows[k] = A32 + (size_t)((b * Nn + nidx[(size_t)p * 8 + k]) * Ll + h) * Cc + q * 24;
    float* dst = nb + (size_t)p * Cc + q * 24;
    #pragma unroll 4
    for (int c = 0; c < 24; ++c) {
        float L = __fadd_rn(__fadd_rn(rows[0][c], rows[1][c]),
                            __fadd_rn(rows[2][c], rows[3][c]));
        float R = __fadd_rn(__fadd_rn(rows[4][c], rows[5][c]),
                            __fadd_rn(rows[6][c], rows[7][c]));
        dst[c] = __fmul_rn(__fadd_rn(L, R), 0.125f);
    }
}

// ---- np-mimic MLP GEMM: out = act(A @ W^T + bias); BLAS-style sequential-k FMA ----
template<int K, bool LEAKY>
__global__ __launch_bounds__(256) void npgemm_kernel(const float* __restrict__ A,
                                                     const float* __restrict__ W,
                                                     const float* __restrict__ bias,
                                                     float* __restrict__ out,
                                                     int N, int ostride) {
    int j = blockIdx.x * 64 + threadIdx.x;
    int i = blockIdx.y * 4 + threadIdx.y;
    if (j >= N) return;
    const float* a = A + (size_t)i * K;
    const float* w = W + (size_t)j * K;
    float acc = 0.f;
    #pragma unroll 8
    for (int k = 0; k < K; ++k) acc = __builtin_fmaf(a[k], w[k], acc);
    float v = __fadd_rn(acc, bias[j]);
    if (LEAKY) v = v > 0.f ? v : __fmul_rn(0.2f, v);
    out[(size_t)i * ostride + j] = v;
}

// ---- swizzled fp32 tile staging for value-path gemm ----
__device__ inline void stage_row(const float* __restrict__ src, float* __restrict__ tile,
                                 int r, int q) {
    const int s = (r >> 2) & 7;
    #pragma unroll
    for (int m = 0; m < 6; ++m) {
        int g = q * 6 + m;
        float4 v = reinterpret_cast<const float4*>(src)[g];
        *reinterpret_cast<float4*>(&tile[r * KP + ((g ^ s) << 2)]) = v;
    }
}

// ---------------- fast fp32 GEMM (value path): out = Ain @ W^T + bias ----------------
template<int K>
__global__ __launch_bounds__(256) void gemm_kernel(const float* __restrict__ Ain,
                                                   const float* __restrict__ W,
                                                   const float* __restrict__ bias,
                                                   float* __restrict__ out,
                                                   int Nout, int out_stride) {
    __shared__ float a_t[64 * KP];
    __shared__ float w_t[64 * KP];
    const int row0 = blockIdx.x * 64;
    const int col0 = blockIdx.y * 64;
    const int tid  = threadIdx.x;
    const int tx   = tid & 15;
    const int ty   = tid >> 4;

    float acc[4][4] = {};
    for (int kt = 0; kt < K; kt += 96) {
        __syncthreads();
        {
            int r = tid >> 2, q = tid & 3;
            stage_row(Ain + (size_t)(row0 + r) * K + kt, a_t, r, q);
            if (col0 + r < Nout) {
                stage_row(W + (size_t)(col0 + r) * K + kt, w_t, r, q);
            } else {
                const int s = (r >> 2) & 7;
                #pragma unroll
                for (int m = 0; m < 6; ++m) {
                    int g = q * 6 + m;
                    *reinterpret_cast<float4*>(&w_t[r * KP + ((g ^ s) << 2)]) =
                        float4{0.f, 0.f, 0.f, 0.f};
                }
            }
        }
        __syncthreads();
        const int sa = ty & 7, sb = tx & 7;
        #pragma unroll 4
        for (int k4 = 0; k4 < 24; ++k4) {
            float4 av[4], bv[4];
            const int ga = (k4 ^ sa) << 2, gb = (k4 ^ sb) << 2;
            #pragma unroll
            for (int i = 0; i < 4; ++i)
                av[i] = *reinterpret_cast<const float4*>(&a_t[(ty * 4 + i) * KP + ga]);
            #pragma unroll
            for (int j = 0; j < 4; ++j)
                bv[j] = *reinterpret_cast<const float4*>(&w_t[(tx * 4 + j) * KP + gb]);
            #pragma unroll
            for (int i = 0; i < 4; ++i)
                #pragma unroll
                for (int j = 0; j < 4; ++j)
                    acc[i][j] += av[i].x * bv[j].x + av[i].y * bv[j].y +
                                 av[i].z * bv[j].z + av[i].w * bv[j].w;
        }
    }
    #pragma unroll
    for (int i = 0; i < 4; ++i) {
        int row = row0 + ty * 4 + i;
        #pragma unroll
        for (int j = 0; j < 4; ++j) {
            int col = col0 + tx * 4 + j;
            if (col < Nout)
                out[(size_t)row * out_stride + col] = acc[i][j] + bias[col];
        }
    }
}

// ---------------- per-(point, head) MHA; mean over 4 slots folded in ----------------
__global__ __launch_bounds__(256) void attn_kernel(const float* __restrict__ qkv,
                                                   float* __restrict__ mbuf) {
    int t  = blockIdx.x * 256 + threadIdx.x;   // 4096*3 threads
    int p  = t / 3;
    int hh = t - p * 3;
    const float* base = qkv + (size_t)p * 4 * 288;
    const float* qb = base + hh * 32;
    const float* kb = base + 96 + hh * 32;
    const float* vb = base + 192 + hh * 32;

    float sc[4][4] = {};
    #pragma unroll
    for (int d = 0; d < 32; d += 4) {
        float4 qv[4], kv[4];
        #pragma unroll
        for (int l = 0; l < 4; ++l) {
            qv[l] = *reinterpret_cast<const float4*>(qb + l * 288 + d);
            kv[l] = *reinterpret_cast<const float4*>(kb + l * 288 + d);
        }
        #pragma unroll
        for (int l = 0; l < 4; ++l)
            #pragma unroll
            for (int m = 0; m < 4; ++m)
                sc[l][m] += qv[l].x * kv[m].x + qv[l].y * kv[m].y +
                            qv[l].z * kv[m].z + qv[l].w * kv[m].w;
    }
    const float scale = 0.17677669529663687f;   // 1/sqrt(32)
    float am[4] = {0.f, 0.f, 0.f, 0.f};
    #pragma unroll
    for (int l = 0; l < 4; ++l) {
        float s0 = sc[l][0] * scale, s1 = sc[l][1] * scale;
        float s2 = sc[l][2] * scale, s3 = sc[l][3] * scale;
        float mx = fmaxf(fmaxf(s0, s1), fmaxf(s2, s3));
        float e0 = expf(s0 - mx), e1 = expf(s1 - mx);
        float e2 = expf(s2 - mx), e3 = expf(s3 - mx);
        float inv = 1.f / (e0 + e1 + e2 + e3);
        am[0] += e0 * inv; am[1] += e1 * inv; am[2] += e2 * inv; am[3] += e3 * inv;
    }
    am[0] *= 0.25f; am[1] *= 0.25f; am[2] *= 0.25f; am[3] *= 0.25f;
    #pragma unroll
    for (int d = 0; d < 32; d += 4) {
        float4 o = {0.f, 0.f, 0.f, 0.f};
        #pragma unroll
        for (int m = 0; m < 4; ++m) {
            float4 v = *reinterpret_cast<const float4*>(vb + m * 288 + d);
            o.x += am[m] * v.x; o.y += am[m] * v.y;
            o.z += am[m] * v.z; o.w += am[m] * v.w;
        }
        *reinterpret_cast<float4*>(mbuf + (size_t)p * 96 + hh * 32 + d) = o;
    }
}

}  // namespace

extern "C" void kernel_launch(void* const* d_in, const int* in_sizes, int n_in,
                              void* d_out, int out_size, void* d_ws, size_t ws_size,
                              hipStream_t stream) {
    const float* xyz = (const float*)d_in[0];
    const float* W1  = (const float*)d_in[1];
    const float* b1  = (const float*)d_in[2];
    const float* W2  = (const float*)d_in[3];
    const float* b2  = (const float*)d_in[4];
    const float* ipw = (const float*)d_in[5];
    const float* ipb = (const float*)d_in[6];
    const float* opw = (const float*)d_in[7];
    const float* opb = (const float*)d_in[8];

    char* ws = (char*)d_ws;
    float*  A32  = (float*)ws;                   // [65536][96]           25.2 MB
    float*  sqnp = (float*)(ws + 25165824);      // [16384]                64 KB
    int*    cand = (int*)  (ws + 25231360);      // [16384][48]           3.1 MB (6.3 reserved)
    int*    nidx = (int*)  (ws + 31522816);      // [16384][8]            512 KB
    float*  nb   = (float*)(ws + 32047104);      // [16384][96]           6.3 MB
    float*  h1   = (float*)(ws + 38338560);      // [16384][192]         12.6 MB
    float*  qkvc = (float*)(ws + 50921472);      // [16384][288]         18.9 MB
    float*  mbuf = (float*)(ws + 69795840);      // [16384][96]           6.3 MB
    ushort* A16  = (ushort*)(ws + 76087296);     // [16384][96] bf16      3.1 MB
    // total ~79.2 MB

    copy_xyz_kernel<<<1536, 256, 0, stream>>>(xyz, A32);

    for (int h = 0; h < 3; ++h) {
        sqnp_kernel<<<64, 256, 0, stream>>>(A32, sqnp, h);
        cvt_kernel<<<768, 256, 0, stream>>>(A32, A16, h);
        knn_mfma_kernel<<<NPTS / 64, 256, 0, stream>>>(A16, sqnp, cand);
        rescore_kernel<<<NPTS / 32, 256, 0, stream>>>(A32, sqnp, cand, nidx, h);
        mean_kernel<<<NPTS / 64, 256, 0, stream>>>(A32, nidx, nb, h);
        npgemm_kernel<96, true><<<dim3(3, NPTS / 4), dim3(64, 4), 0, stream>>>(
            nb, W1 + (size_t)h * 192 * 96, b1 + h * 192, h1, 192, 192);
        npgemm_kernel<192, false><<<dim3(2, NPTS / 4), dim3(64, 4), 0, stream>>>(
            h1, W2 + (size_t)h * 96 * 192, b2 + h * 96, A32 + (h + 1) * 96, 96, Ll * Cc);
    }

    // MHA (value path), chunked per batch
    for (int b = 0; b < Bb; ++b) {
        gemm_kernel<96><<<dim3(16384 / 64, 5), 256, 0, stream>>>(
            A32 + (size_t)b * 4096 * Ll * Cc, ipw, ipb, qkvc, 288, 288);
        attn_kernel<<<48, 256, 0, stream>>>(qkvc, mbuf + (size_t)b * 4096 * 96);
    }

    gemm_kernel<96><<<dim3(NPTS / 64, 2), 256, 0, stream>>>(
        mbuf, opw, opb, (float*)d_out, 96, 96);
}

// Round 9
// 2631.146 us; speedup vs baseline: 3.3932x; 1.5414x over previous
//
#include <hip/hip_runtime.h>
#include <cfloat>

namespace {

constexpr int Bb    = 4;
constexpr int Nn    = 4096;
constexpr int Cc    = 96;
constexpr int Ll    = 4;           // hops+1 slots
constexpr int NPTS  = Bb * Nn;     // 16384
constexpr int C4    = Cc / 4;      // 24
constexpr int KP    = 100;         // padded LDS row stride (floats) for fp32 gemm
constexpr int CS    = 2;           // column splits of the db dimension
constexpr int TK    = 12;          // per-lane candidates
constexpr int NCROW = CS * 4 * TK; // 96 candidates per row
constexpr int LP    = 104;         // bf16 LDS row pitch (208 B)

typedef __attribute__((ext_vector_type(8))) short bf16x8;
typedef __attribute__((ext_vector_type(4))) float f32x4;

// RNE fp32 -> bf16 (candidate ranking only)
__device__ inline ushort f2bf(float x) {
    unsigned u = __float_as_uint(x);
    return (ushort)((u + 0x7FFF + ((u >> 16) & 1)) >> 16);
}

// lexicographic (value, index) sorted-insert into ascending top-T
template<int T>
__device__ inline void lexins(float v, int vi, float (&bd)[T], int (&bi)[T]) {
    if (v < bd[T - 1] || (v == bd[T - 1] && vi < bi[T - 1])) {
        #pragma unroll
        for (int t = 0; t < T; ++t) {
            if (v < bd[t] || (v == bd[t] && vi < bi[t])) {
                float tv = bd[t]; bd[t] = v;  v  = tv;
                int   ti = bi[t]; bi[t] = vi; vi = ti;
            }
        }
    }
}

// ---------------- copy xyz into stacked slot 0 ----------------
__global__ __launch_bounds__(256) void copy_xyz_kernel(const float* __restrict__ xyz,
                                                       float* __restrict__ A32) {
    int f = blockIdx.x * 256 + threadIdx.x;           // float4 index over [NPTS][C4]
    int p = f / C4;
    int c4 = f - p * C4;
    float4 v = reinterpret_cast<const float4*>(xyz)[f];
    reinterpret_cast<float4*>(A32)[(size_t)(p * Ll) * C4 + c4] = v;
}

// ---------------- np-mimic sq: numpy pairwise-8 over 96 of fl(x*x) ----------------
__global__ __launch_bounds__(256) void sqnp_kernel(const float* __restrict__ A32,
                                                   float* __restrict__ sqnp, int h) {
    int p = blockIdx.x * 256 + threadIdx.x;
    const float* x = A32 + (size_t)(p * Ll + h) * Cc;
    float r[8];
    #pragma unroll
    for (int j = 0; j < 8; ++j) r[j] = __fmul_rn(x[j], x[j]);
    #pragma unroll
    for (int i = 8; i < 96; i += 8)
        #pragma unroll
        for (int j = 0; j < 8; ++j) r[j] = __fadd_rn(r[j], __fmul_rn(x[i + j], x[i + j]));
    float L = __fadd_rn(__fadd_rn(r[0], r[1]), __fadd_rn(r[2], r[3]));
    float R = __fadd_rn(__fadd_rn(r[4], r[5]), __fadd_rn(r[6], r[7]));
    sqnp[p] = __fadd_rn(L, R);
}

// ---------------- fp32 slot h -> bf16 feature matrix A16[16384][96] ----------------
__global__ __launch_bounds__(256) void cvt_kernel(const float* __restrict__ A32,
                                                  ushort* __restrict__ A16, int h) {
    int t = blockIdx.x * 256 + threadIdx.x;           // 16384*12 groups of 8 elems
    int p = t / 12, j = t - p * 12;
    const float4* s = reinterpret_cast<const float4*>(A32 + (size_t)(p * Ll + h) * Cc + j * 8);
    float4 v0 = s[0], v1 = s[1];
    uint4 o;
    o.x = (unsigned)f2bf(v0.x) | ((unsigned)f2bf(v0.y) << 16);
    o.y = (unsigned)f2bf(v0.z) | ((unsigned)f2bf(v0.w) << 16);
    o.z = (unsigned)f2bf(v1.x) | ((unsigned)f2bf(v1.y) << 16);
    o.w = (unsigned)f2bf(v1.z) | ((unsigned)f2bf(v1.w) << 16);
    *reinterpret_cast<uint4*>(A16 + (size_t)p * 96 + j * 8) = o;
}

// ---- MFMA candidate pass: D[db][q] = DB·Q^T via 16x16x32 bf16; defer-batched top-12 ----
// grid (NPTS/64, CS), block 256 (4 waves x 16 queries). Each block scans 2048 db rows
// of the query's batch in 64-row chunks. C-layout (m89): col=lane&15 (query),
// row=(lane>>4)*4+reg (db). Scan: cheap threshold guard + mask; spill keys to
// lane-private LDS; ctz-loop runs the insert chain only for actual takes.
__global__ __launch_bounds__(256) void knn_mfma_kernel(const ushort* __restrict__ A16,
                                                       const float* __restrict__ sqnp,
                                                       int* __restrict__ cand) {
    __shared__ ushort qt[64 * LP];          // 13312 B
    __shared__ ushort dbt[2][64 * LP];      // 26624 B (double buffer)
    __shared__ float  sqf[2][64];           //   512 B
    __shared__ float  klds[256 * 17];       // 17408 B key scratch (stride 17: no conflicts)

    const int q0    = blockIdx.x * 64;
    const int cs    = blockIdx.y;
    const int pbase = (q0 >> 12) << 12;     // batch base
    const int col0  = cs * (Nn / CS);       // this block's db half
    const int tid   = threadIdx.x;
    const int w     = tid >> 6;
    const int l     = tid & 63;
    constexpr int NCH = (Nn / CS) / 64;     // 32 chunks

    {   // stage Q tile + chunk 0
        int r = tid >> 2, q = tid & 3;
        const uint4* s = reinterpret_cast<const uint4*>(A16 + (size_t)(q0 + r) * 96 + q * 24);
        uint4* d = reinterpret_cast<uint4*>(qt + r * LP + q * 24);
        d[0] = s[0]; d[1] = s[1]; d[2] = s[2];
        const uint4* s2 = reinterpret_cast<const uint4*>(
            A16 + (size_t)(pbase + col0 + r) * 96 + q * 24);
        uint4* d2 = reinterpret_cast<uint4*>(dbt[0] + r * LP + q * 24);
        d2[0] = s2[0]; d2[1] = s2[1]; d2[2] = s2[2];
    }
    if (tid < 64) sqf[0][tid] = sqnp[pbase + col0 + tid];
    __syncthreads();

    // B fragments (this wave's 16 queries), constant across chunks.
    const int qrow = w * 16 + (l & 15);
    const int koff = (l >> 4) * 8;
    bf16x8 bq[3];
    #pragma unroll
    for (int s = 0; s < 3; ++s)
        bq[s] = *reinterpret_cast<const bf16x8*>(qt + qrow * LP + koff + 32 * s);

    float bd[TK]; int bi[TK];
    #pragma unroll
    for (int t = 0; t < TK; ++t) { bd[t] = FLT_MAX; bi[t] = 0x7fffffff; }
    float kd = FLT_MAX; int ki = 0x7fffffff;      // cached 12th-best threshold

    for (int c = 0; c < NCH; ++c) {
        const int buf = c & 1;
        if (c + 1 < NCH) {   // prefetch next chunk into other buffer
            int r = tid >> 2, q = tid & 3;
            const uint4* s = reinterpret_cast<const uint4*>(
                A16 + (size_t)(pbase + col0 + (c + 1) * 64 + r) * 96 + q * 24);
            uint4* d = reinterpret_cast<uint4*>(dbt[buf ^ 1] + r * LP + q * 24);
            d[0] = s[0]; d[1] = s[1]; d[2] = s[2];
            if (tid < 64) sqf[buf ^ 1][tid] = sqnp[pbase + col0 + (c + 1) * 64 + tid];
        }

        f32x4 acc[4];
        #pragma unroll
        for (int sub = 0; sub < 4; ++sub) {
            acc[sub] = f32x4{0.f, 0.f, 0.f, 0.f};
            #pragma unroll
            for (int s = 0; s < 3; ++s) {
                bf16x8 a = *reinterpret_cast<const bf16x8*>(
                    dbt[buf] + (sub * 16 + (l & 15)) * LP + koff + 32 * s);
                acc[sub] = __builtin_amdgcn_mfma_f32_16x16x32_bf16(a, bq[s], acc[sub], 0, 0, 0);
            }
        }

        // cheap guard + key spill; insert chain deferred to actual takes only
        const int cbase = col0 + c * 64;
        unsigned mask = 0;
        #pragma unroll
        for (int sub = 0; sub < 4; ++sub)
            #pragma unroll
            for (int r = 0; r < 4; ++r) {
                const int s = sub * 4 + r;
                const int dl = sub * 16 + (l >> 4) * 4 + r;
                float v = sqf[buf][dl] - 2.f * acc[sub][r];
                klds[tid * 17 + s] = v;
                int vi = cbase + dl;
                bool take = (v < kd) || (v == kd && vi < ki);
                mask |= (unsigned)take << s;
            }
        while (mask) {
            int s = __builtin_ctz(mask); mask &= mask - 1;
            float v = klds[tid * 17 + s];
            int dl = ((s >> 2) << 4) + ((l >> 4) << 2) + (s & 3);
            lexins<TK>(v, cbase + dl, bd, bi);
            kd = bd[TK - 1]; ki = bi[TK - 1];
        }
        __syncthreads();   // chunk consumed; prefetched buffer complete
    }

    const int qg = q0 + qrow;
    #pragma unroll
    for (int t = 0; t < TK; ++t)
        cand[(size_t)qg * NCROW + (cs * 4 + (l >> 4)) * TK + t] = bi[t];
}

// ---- np-mimic einsum dot: SSE SOP path — 4-lane mul+add accumulators, hadd combine ----
__device__ inline float dot_np(const float* __restrict__ xn, const float* __restrict__ xm) {
    float l0 = 0.f, l1 = 0.f, l2 = 0.f, l3 = 0.f;
    #pragma unroll
    for (int t = 0; t < 96; t += 4) {
        float4 a = *reinterpret_cast<const float4*>(xn + t);
        float4 c = *reinterpret_cast<const float4*>(xm + t);
        l0 = __fadd_rn(l0, __fmul_rn(a.x, c.x));
        l1 = __fadd_rn(l1, __fmul_rn(a.y, c.y));
        l2 = __fadd_rn(l2, __fmul_rn(a.z, c.z));
        l3 = __fadd_rn(l3, __fmul_rn(a.w, c.w));
    }
    return __fadd_rn(__fadd_rn(l0, l1), __fadd_rn(l2, l3));
}

// ---- np-exact rescore of 96 candidates -> stable top-8 by (d2, idx) ----
// 8 threads per query score 12 candidates each; thread 0 of the 8 merges.
__global__ __launch_bounds__(256) void rescore_kernel(const float* __restrict__ A32,
                                                      const float* __restrict__ sqnp,
                                                      const int* __restrict__ cand,
                                                      int* __restrict__ nidx, int h) {
    __shared__ float sc[32][NCROW];
    const int tid  = threadIdx.x;
    const int qloc = tid >> 3, sub = tid & 7;
    const int p    = blockIdx.x * 32 + qloc;
    const int base = (p >> 12) << 12;
    const float* xn = A32 + (size_t)(p * Ll + h) * Cc;
    const float sqn = sqnp[p];
    const int* cp = cand + (size_t)p * NCROW;

    #pragma unroll
    for (int c = 0; c < NCROW / 8; ++c) {
        int m = cp[sub * (NCROW / 8) + c];
        const float* xm = A32 + (size_t)((base + m) * Ll + h) * Cc;
        float dot = dot_np(xn, xm);
        // np: d2 = fl(fl(sq_n + sq_m) - fl(2*dot))
        sc[qloc][sub * (NCROW / 8) + c] =
            __fsub_rn(__fadd_rn(sqn, sqnp[base + m]), __fmul_rn(2.0f, dot));
    }
    __syncthreads();
    if (sub == 0) {
        float sd[8]; int si[8];
        #pragma unroll
        for (int t = 0; t < 8; ++t) { sd[t] = FLT_MAX; si[t] = 0x7fffffff; }
        #pragma unroll 1
        for (int c = 0; c < NCROW; ++c) lexins<8>(sc[qloc][c], cp[c], sd, si);
        #pragma unroll
        for (int t = 0; t < 8; ++t) nidx[(size_t)p * 8 + t] = si[t];
    }
}

// ---- np-mimic neighbor mean: pairwise-8 tree, x0.125 ----
__global__ __launch_bounds__(256) void mean_kernel(const float* __restrict__ A32,
                                                   const int* __restrict__ nidx,
                                                   float* __restrict__ nb, int h) {
    const int p = blockIdx.x * 64 + (threadIdx.x >> 2);
    const int q = threadIdx.x & 3;
    const int b = p >> 12;
    const float* rows[8];
    #pragma unroll
    for (int k = 0; k < 8; ++k)
        rows[k] = A32 + (size_t)((b * Nn + nidx[(size_t)p * 8 + k]) * Ll + h) * Cc + q * 24;
    float* dst = nb + (size_t)p * Cc + q * 24;
    #pragma unroll 4
    for (int c = 0; c < 24; ++c) {
        float L = __fadd_rn(__fadd_rn(rows[0][c], rows[1][c]),
                            __fadd_rn(rows[2][c], rows[3][c]));
        float R = __fadd_rn(__fadd_rn(rows[4][c], rows[5][c]),
                            __fadd_rn(rows[6][c], rows[7][c]));
        dst[c] = __fmul_rn(__fadd_rn(L, R), 0.125f);
    }
}

// ---- np-mimic MLP GEMM: out = act(A @ W^T + bias); BLAS-style sequential-k FMA ----
template<int K, bool LEAKY>
__global__ __launch_bounds__(256) void npgemm_kernel(const float* __restrict__ A,
                                                     const float* __restrict__ W,
                                                     const float* __restrict__ bias,
                                                     float* __restrict__ out,
                                                     int N, int ostride) {
    int j = blockIdx.x * 64 + threadIdx.x;
    int i = blockIdx.y * 4 + threadIdx.y;
    if (j >= N) return;
    const float* a = A + (size_t)i * K;
    const float* w = W + (size_t)j * K;
    float acc = 0.f;
    #pragma unroll 8
    for (int k = 0; k < K; ++k) acc = __builtin_fmaf(a[k], w[k], acc);
    float v = __fadd_rn(acc, bias[j]);
    if (LEAKY) v = v > 0.f ? v : __fmul_rn(0.2f, v);
    out[(size_t)i * ostride + j] = v;
}

// ---- swizzled fp32 tile staging for value-path gemm ----
__device__ inline void stage_row(const float* __restrict__ src, float* __restrict__ tile,
                                 int r, int q) {
    const int s = (r >> 2) & 7;
    #pragma unroll
    for (int m = 0; m < 6; ++m) {
        int g = q * 6 + m;
        float4 v = reinterpret_cast<const float4*>(src)[g];
        *reinterpret_cast<float4*>(&tile[r * KP + ((g ^ s) << 2)]) = v;
    }
}

// ---------------- fast fp32 GEMM (value path): out = Ain @ W^T + bias ----------------
template<int K>
__global__ __launch_bounds__(256) void gemm_kernel(const float* __restrict__ Ain,
                                                   const float* __restrict__ W,
                                                   const float* __restrict__ bias,
                                                   float* __restrict__ out,
                                                   int Nout, int out_stride) {
    __shared__ float a_t[64 * KP];
    __shared__ float w_t[64 * KP];
    const int row0 = blockIdx.x * 64;
    const int col0 = blockIdx.y * 64;
    const int tid  = threadIdx.x;
    const int tx   = tid & 15;
    const int ty   = tid >> 4;

    float acc[4][4] = {};
    for (int kt = 0; kt < K; kt += 96) {
        __syncthreads();
        {
            int r = tid >> 2, q = tid & 3;
            stage_row(Ain + (size_t)(row0 + r) * K + kt, a_t, r, q);
            if (col0 + r < Nout) {
                stage_row(W + (size_t)(col0 + r) * K + kt, w_t, r, q);
            } else {
                const int s = (r >> 2) & 7;
                #pragma unroll
                for (int m = 0; m < 6; ++m) {
                    int g = q * 6 + m;
                    *reinterpret_cast<float4*>(&w_t[r * KP + ((g ^ s) << 2)]) =
                        float4{0.f, 0.f, 0.f, 0.f};
                }
            }
        }
        __syncthreads();
        const int sa = ty & 7, sb = tx & 7;
        #pragma unroll 4
        for (int k4 = 0; k4 < 24; ++k4) {
            float4 av[4], bv[4];
            const int ga = (k4 ^ sa) << 2, gb = (k4 ^ sb) << 2;
            #pragma unroll
            for (int i = 0; i < 4; ++i)
                av[i] = *reinterpret_cast<const float4*>(&a_t[(ty * 4 + i) * KP + ga]);
            #pragma unroll
            for (int j = 0; j < 4; ++j)
                bv[j] = *reinterpret_cast<const float4*>(&w_t[(tx * 4 + j) * KP + gb]);
            #pragma unroll
            for (int i = 0; i < 4; ++i)
                #pragma unroll
                for (int j = 0; j < 4; ++j)
                    acc[i][j] += av[i].x * bv[j].x + av[i].y * bv[j].y +
                                 av[i].z * bv[j].z + av[i].w * bv[j].w;
        }
    }
    #pragma unroll
    for (int i = 0; i < 4; ++i) {
        int row = row0 + ty * 4 + i;
        #pragma unroll
        for (int j = 0; j < 4; ++j) {
            int col = col0 + tx * 4 + j;
            if (col < Nout)
                out[(size_t)row * out_stride + col] = acc[i][j] + bias[col];
        }
    }
}

// ---------------- per-(point, head) MHA; mean over 4 slots folded in ----------------
__global__ __launch_bounds__(256) void attn_kernel(const float* __restrict__ qkv,
                                                   float* __restrict__ mbuf) {
    int t  = blockIdx.x * 256 + threadIdx.x;   // 4096*3 threads
    int p  = t / 3;
    int hh = t - p * 3;
    const float* base = qkv + (size_t)p * 4 * 288;
    const float* qb = base + hh * 32;
    const float* kb = base + 96 + hh * 32;
    const float* vb = base + 192 + hh * 32;

    float sc[4][4] = {};
    #pragma unroll
    for (int d = 0; d < 32; d += 4) {
        float4 qv[4], kv[4];
        #pragma unroll
        for (int l = 0; l < 4; ++l) {
            qv[l] = *reinterpret_cast<const float4*>(qb + l * 288 + d);
            kv[l] = *reinterpret_cast<const float4*>(kb + l * 288 + d);
        }
        #pragma unroll
        for (int l = 0; l < 4; ++l)
            #pragma unroll
            for (int m = 0; m < 4; ++m)
                sc[l][m] += qv[l].x * kv[m].x + qv[l].y * kv[m].y +
                            qv[l].z * kv[m].z + qv[l].w * kv[m].w;
    }
    const float scale = 0.17677669529663687f;   // 1/sqrt(32)
    float am[4] = {0.f, 0.f, 0.f, 0.f};
    #pragma unroll
    for (int l = 0; l < 4; ++l) {
        float s0 = sc[l][0] * scale, s1 = sc[l][1] * scale;
        float s2 = sc[l][2] * scale, s3 = sc[l][3] * scale;
        float mx = fmaxf(fmaxf(s0, s1), fmaxf(s2, s3));
        float e0 = expf(s0 - mx), e1 = expf(s1 - mx);
        float e2 = expf(s2 - mx), e3 = expf(s3 - mx);
        float inv = 1.f / (e0 + e1 + e2 + e3);
        am[0] += e0 * inv; am[1] += e1 * inv; am[2] += e2 * inv; am[3] += e3 * inv;
    }
    am[0] *= 0.25f; am[1] *= 0.25f; am[2] *= 0.25f; am[3] *= 0.25f;
    #pragma unroll
    for (int d = 0; d < 32; d += 4) {
        float4 o = {0.f, 0.f, 0.f, 0.f};
        #pragma unroll
        for (int m = 0; m < 4; ++m) {
            float4 v = *reinterpret_cast<const float4*>(vb + m * 288 + d);
            o.x += am[m] * v.x; o.y += am[m] * v.y;
            o.z += am[m] * v.z; o.w += am[m] * v.w;
        }
        *reinterpret_cast<float4*>(mbuf + (size_t)p * 96 + hh * 32 + d) = o;
    }
}

}  // namespace

extern "C" void kernel_launch(void* const* d_in, const int* in_sizes, int n_in,
                              void* d_out, int out_size, void* d_ws, size_t ws_size,
                              hipStream_t stream) {
    const float* xyz = (const float*)d_in[0];
    const float* W1  = (const float*)d_in[1];
    const float* b1  = (const float*)d_in[2];
    const float* W2  = (const float*)d_in[3];
    const float* b2  = (const float*)d_in[4];
    const float* ipw = (const float*)d_in[5];
    const float* ipb = (const float*)d_in[6];
    const float* opw = (const float*)d_in[7];
    const float* opb = (const float*)d_in[8];

    char* ws = (char*)d_ws;
    float*  A32  = (float*)ws;                   // [65536][96]           25.2 MB
    float*  sqnp = (float*)(ws + 25165824);      // [16384]                64 KB
    int*    cand = (int*)  (ws + 25231360);      // [16384][96]           6.3 MB
    int*    nidx = (int*)  (ws + 31522816);      // [16384][8]            512 KB
    float*  nb   = (float*)(ws + 32047104);      // [16384][96]           6.3 MB
    float*  h1   = (float*)(ws + 38338560);      // [16384][192]         12.6 MB
    float*  qkvc = (float*)(ws + 50921472);      // [16384][288]         18.9 MB
    float*  mbuf = (float*)(ws + 69795840);      // [16384][96]           6.3 MB
    ushort* A16  = (ushort*)(ws + 76087296);     // [16384][96] bf16      3.1 MB
    // total ~79.2 MB

    copy_xyz_kernel<<<1536, 256, 0, stream>>>(xyz, A32);

    for (int h = 0; h < 3; ++h) {
        sqnp_kernel<<<64, 256, 0, stream>>>(A32, sqnp, h);
        cvt_kernel<<<768, 256, 0, stream>>>(A32, A16, h);
        knn_mfma_kernel<<<dim3(NPTS / 64, CS), 256, 0, stream>>>(A16, sqnp, cand);
        rescore_kernel<<<NPTS / 32, 256, 0, stream>>>(A32, sqnp, cand, nidx, h);
        mean_kernel<<<NPTS / 64, 256, 0, stream>>>(A32, nidx, nb, h);
        npgemm_kernel<96, true><<<dim3(3, NPTS / 4), dim3(64, 4), 0, stream>>>(
            nb, W1 + (size_t)h * 192 * 96, b1 + h * 192, h1, 192, 192);
        npgemm_kernel<192, false><<<dim3(2, NPTS / 4), dim3(64, 4), 0, stream>>>(
            h1, W2 + (size_t)h * 96 * 192, b2 + h * 96, A32 + (h + 1) * 96, 96, Ll * Cc);
    }

    // MHA (value path), chunked per batch
    for (int b = 0; b < Bb; ++b) {
        gemm_kernel<96><<<dim3(16384 / 64, 5), 256, 0, stream>>>(
            A32 + (size_t)b * 4096 * Ll * Cc, ipw, ipb, qkvc, 288, 288);
        attn_kernel<<<48, 256, 0, stream>>>(qkvc, mbuf + (size_t)b * 4096 * 96);
    }

    gemm_kernel<96><<<dim3(NPTS / 64, 2), 256, 0, stream>>>(
        mbuf, opw, opb, (float*)d_out, 96, 96);
}